// Round 1
// baseline (4540.792 us; speedup 1.0000x reference)
//
#include <hip/hip_runtime.h>
#include <hip/hip_bf16.h>
#include <math.h>

// ---------------- constants ----------------
#define BATCH 64
#define SEQ   18
#define DMODEL 800
#define NHEAD 8
#define HDIM  100
#define NLAYER 8
#define DFF   3200

typedef short short8 __attribute__((ext_vector_type(8)));
typedef float f32x4 __attribute__((ext_vector_type(4)));

// workspace layout (in floats)
#define OFF_PE    0L
#define OFF_STATS 14400L
#define OFF_WR1   14912L
#define OFF_C1    34208L
#define OFF_C2    955808L
#define OFF_P     1877408L
#define OFF_C3    6596000L
#define OFF_X     7517600L
#define OFF_XA    8439200L
#define OFF_QKV   9360800L
#define OFF_O     12125600L
#define OFF_AB    13047200L
#define OFF_H     13968800L
// total = 17655200 floats = 70.6 MB

// ---------------- helpers ----------------
__device__ __forceinline__ unsigned short bf16_rn(float x){
  unsigned int u = __float_as_uint(x);
  unsigned int r = u + 0x7FFFu + ((u >> 16) & 1u);
  return (unsigned short)(r >> 16);
}
__device__ __forceinline__ float bf16_to_f(unsigned short h){
  return __uint_as_float(((unsigned int)h) << 16);
}
__device__ __forceinline__ float gelu_f(float x){
  float u = 0.7978845608028654f * (x + 0.044715f * x * x * x);
  return 0.5f * x * (1.0f + tanhf(u));
}

// block reduction of (s,q); result valid in tid==0. red[] must hold >=16 floats.
__device__ __forceinline__ void block_reduce_2(float &s, float &q, float* red, int tid){
  #pragma unroll
  for (int off = 32; off > 0; off >>= 1){
    s += __shfl_down(s, off, 64);
    q += __shfl_down(q, off, 64);
  }
  int w = tid >> 6;
  if ((tid & 63) == 0){ red[w] = s; red[8 + w] = q; }
  __syncthreads();
  if (tid == 0){
    float ss = 0.f, qq = 0.f;
    int nw = blockDim.x >> 6;
    for (int i = 0; i < nw; ++i){ ss += red[i]; qq += red[8 + i]; }
    s = ss; q = qq;
  }
}

// ---------------- tiny utility kernels ----------------
__global__ __launch_bounds__(256) void zero_kernel(float* p, int n){
  int i = blockIdx.x * 256 + threadIdx.x;
  if (i < n) p[i] = 0.f;
}

__global__ __launch_bounds__(256) void relayout_w1_kernel(const float* __restrict__ w1, float* __restrict__ wr){
  int idx = blockIdx.x * 256 + threadIdx.x;
  if (idx >= 8 * 12 * 201) return;
  int o = idx / 2412, rem = idx % 2412, i = rem / 201, t = rem % 201;
  wr[(i * 201 + t) * 8 + o] = w1[idx];
}

__global__ __launch_bounds__(256) void pe_kernel(float* __restrict__ pe){
  int idx = blockIdx.x * 256 + threadIdx.x;
  if (idx >= SEQ * DMODEL) return;
  int s = idx / DMODEL, d = idx % DMODEL;
  int j = d >> 1;
  float div = expf(-9.210340371976184f * (float)(2 * j) / 800.f);
  float a = (float)s * div;
  pe[idx] = (d & 1) ? cosf(a) : sinf(a);
}

// ---------------- conv1: [64,12,9000] -> [64,8,1800], stride 5, K=201, pad 100 ----------------
__global__ __launch_bounds__(256) void conv1_kernel(const float* __restrict__ src,
                                                    const float* __restrict__ wr,
                                                    const float* __restrict__ cb1,
                                                    float* __restrict__ out,
                                                    float* __restrict__ stats){
  __shared__ float sL[12 * 1480];
  __shared__ float red[16];
  const int tid = threadIdx.x;
  const int b = blockIdx.y;
  const int l0 = blockIdx.x * 256;
  const int sstart = 5 * l0 - 100;
  for (int idx = tid; idx < 12 * 1480; idx += 256){
    int i = idx / 1480, u = idx % 1480;
    int p = sstart + u;
    sL[idx] = (p >= 0 && p < 9000) ? src[((long)b * 12 + i) * 9000 + p] : 0.f;
  }
  __syncthreads();
  const int l = l0 + tid;
  float acc[8];
  #pragma unroll
  for (int o = 0; o < 8; o++) acc[o] = cb1[o];
  {
    const int base = 5 * tid;
    for (int i = 0; i < 12; i++){
      const float* sp = sL + i * 1480 + base;
      const float* wp = wr + i * 201 * 8;
      for (int t = 0; t < 201; t++){
        float x = sp[t];
        const float4 w0 = *(const float4*)(wp + t * 8);
        const float4 w1 = *(const float4*)(wp + t * 8 + 4);
        acc[0] += x * w0.x; acc[1] += x * w0.y; acc[2] += x * w0.z; acc[3] += x * w0.w;
        acc[4] += x * w1.x; acc[5] += x * w1.y; acc[6] += x * w1.z; acc[7] += x * w1.w;
      }
    }
  }
  float s = 0.f, q = 0.f;
  if (l < 1800){
    #pragma unroll
    for (int o = 0; o < 8; o++){
      out[((long)b * 8 + o) * 1800 + l] = acc[o];
      s += acc[o]; q += acc[o] * acc[o];
    }
  }
  block_reduce_2(s, q, red, tid);
  if (tid == 0){
    atomicAdd(&stats[b * 2 + 0], s);
    atomicAdd(&stats[b * 2 + 1], q);
  }
}

// GroupNorm(1) finalize + GELU, in place. n_per_b = C*L.
__global__ __launch_bounds__(256) void gn_gelu_kernel(float* __restrict__ x,
                                                      const float* __restrict__ stats,
                                                      const float* __restrict__ g,
                                                      const float* __restrict__ bta,
                                                      int L, int n_per_b){
  long idx = (long)blockIdx.x * 256 + threadIdx.x;
  long total = (long)BATCH * n_per_b;
  if (idx >= total) return;
  int b = (int)(idx / n_per_b);
  int rem = (int)(idx % n_per_b);
  int c = rem / L;
  float inv_n = 1.f / (float)n_per_b;
  float m = stats[b * 2] * inv_n;
  float var = stats[b * 2 + 1] * inv_n - m * m;
  float rstd = rsqrtf(var + 1e-5f);
  float v = x[idx];
  v = (v - m) * rstd * g[c] + bta[c];
  x[idx] = gelu_f(v);
}

// ---------------- conv2: [64,8,1800] -> [64,80,180], stride 10, K=101, pad 50 ----------------
__global__ __launch_bounds__(256) void conv2_kernel(const float* __restrict__ in,
                                                    const float* __restrict__ w2,
                                                    const float* __restrict__ cb2,
                                                    float* __restrict__ out,
                                                    float* __restrict__ stats){
  __shared__ float sL[14400];
  __shared__ float red[16];
  const int tid = threadIdx.x;
  const int b = blockIdx.y;
  for (int idx = tid; idx < 14400; idx += 256)
    sL[idx] = in[(long)b * 14400 + idx];
  __syncthreads();
  int j = blockIdx.x * 256 + tid;
  float s = 0.f, q = 0.f;
  if (j < 14400){
    int o = j / 180, l = j % 180;
    float acc = cb2[o];
    const float* wo = w2 + o * 808;
    int base = 10 * l - 50;
    for (int i = 0; i < 8; i++){
      const float* row = sL + i * 1800;
      const float* wi = wo + i * 101;
      int t0 = (base < 0) ? -base : 0;
      int t1 = (base + 101 > 1800) ? (1800 - base) : 101;
      for (int t = t0; t < t1; ++t) acc += row[base + t] * wi[t];
    }
    out[(long)b * 14400 + j] = acc;
    s = acc; q = acc * acc;
  }
  block_reduce_2(s, q, red, tid);
  if (tid == 0){
    atomicAdd(&stats[b * 2 + 0], s);
    atomicAdd(&stats[b * 2 + 1], q);
  }
}

// ---------------- im2col for conv3 as GEMM: P[n=b*18+l][k=i*51+t], ld 4096 ----------------
__global__ __launch_bounds__(256) void im2col_kernel(const float* __restrict__ c2, float* __restrict__ P){
  int idx = blockIdx.x * 256 + threadIdx.x;
  if (idx >= 1152 * 4080) return;
  int n = idx / 4080, k = idx % 4080;
  int b = n / 18, l = n % 18;
  int i = k / 51, t = k % 51;
  int p = 10 * l - 25 + t;
  float v = (p >= 0 && p < 180) ? c2[((long)b * 80 + i) * 180 + p] : 0.f;
  P[(long)n * 4096 + k] = v;
}

// ---------------- split-bf16 MFMA GEMM: C[m][n] = sum_k A[m][k]*B[n][k] (+bias[n]) ----------------
// 128x128 tile, BK=32, 4 waves (each 64x64 = 4x4 frags of 16x16x32).
template<int ACT>  // 0 = none, 1 = gelu
__global__ __launch_bounds__(256, 2)
void gemm_split(const float* __restrict__ A, const float* __restrict__ B,
                const float* __restrict__ bias, float* __restrict__ C,
                int M, int N, int K, int lda, int ldb, int ldc){
  __shared__ unsigned short Ah[128 * 40], Al[128 * 40], Bh[128 * 40], Bl[128 * 40];
  const int tid = threadIdx.x;
  const int lane = tid & 63;
  const int wid = tid >> 6;
  const int wm = (wid >> 1) * 64, wn = (wid & 1) * 64;
  const int tileM = blockIdx.y * 128, tileN = blockIdx.x * 128;

  const int sr = tid >> 1;   // staging row 0..127
  const int sh = tid & 1;    // which 16-wide half of the 32-k tile
  const long aoff = (long)(tileM + sr) * lda;
  const long boff = (long)(tileN + sr) * ldb;
  const bool aok = (tileM + sr) < M;
  const bool bok = (tileN + sr) < N;

  float abuf[16] __attribute__((aligned(16)));
  float bbuf[16] __attribute__((aligned(16)));
  const int NT = (K + 31) / 32;

  // prologue load (k-tile 0)
  {
    int k0 = sh * 16;
    #pragma unroll
    for (int j = 0; j < 16; j += 4){
      int k = k0 + j;
      if (aok && k + 3 < K) *(float4*)&abuf[j] = *(const float4*)(A + aoff + k);
      else { for (int qq = 0; qq < 4; qq++) abuf[j+qq] = (aok && k+qq < K) ? A[aoff + k + qq] : 0.f; }
      if (bok && k + 3 < K) *(float4*)&bbuf[j] = *(const float4*)(B + boff + k);
      else { for (int qq = 0; qq < 4; qq++) bbuf[j+qq] = (bok && k+qq < K) ? B[boff + k + qq] : 0.f; }
    }
  }

  f32x4 acc[4][4];
  #pragma unroll
  for (int i = 0; i < 4; i++)
    #pragma unroll
    for (int j = 0; j < 4; j++)
      acc[i][j] = (f32x4){0.f, 0.f, 0.f, 0.f};

  for (int kt = 0; kt < NT; ++kt){
    __syncthreads();
    // convert current regs -> hi/lo bf16, write LDS (row stride 40 ushorts = 80B, conflict-light)
    {
      const int base = sr * 40 + sh * 16;
      short8 va0, va1, xa0, xa1, vb0, vb1, xb0, xb1;
      #pragma unroll
      for (int j = 0; j < 8; j++){
        { float a = abuf[j];   unsigned short h = bf16_rn(a); va0[j] = (short)h; xa0[j] = (short)bf16_rn(a - bf16_to_f(h)); }
        { float a = abuf[j+8]; unsigned short h = bf16_rn(a); va1[j] = (short)h; xa1[j] = (short)bf16_rn(a - bf16_to_f(h)); }
        { float v = bbuf[j];   unsigned short h = bf16_rn(v); vb0[j] = (short)h; xb0[j] = (short)bf16_rn(v - bf16_to_f(h)); }
        { float v = bbuf[j+8]; unsigned short h = bf16_rn(v); vb1[j] = (short)h; xb1[j] = (short)bf16_rn(v - bf16_to_f(h)); }
      }
      *(short8*)&Ah[base] = va0; *(short8*)&Ah[base + 8] = va1;
      *(short8*)&Al[base] = xa0; *(short8*)&Al[base + 8] = xa1;
      *(short8*)&Bh[base] = vb0; *(short8*)&Bh[base + 8] = vb1;
      *(short8*)&Bl[base] = xb0; *(short8*)&Bl[base + 8] = xb1;
    }
    __syncthreads();
    // prefetch next k-tile (overlaps with MFMA below)
    if (kt + 1 < NT){
      int k0 = (kt + 1) * 32 + sh * 16;
      #pragma unroll
      for (int j = 0; j < 16; j += 4){
        int k = k0 + j;
        if (aok && k + 3 < K) *(float4*)&abuf[j] = *(const float4*)(A + aoff + k);
        else { for (int qq = 0; qq < 4; qq++) abuf[j+qq] = (aok && k+qq < K) ? A[aoff + k + qq] : 0.f; }
        if (bok && k + 3 < K) *(float4*)&bbuf[j] = *(const float4*)(B + boff + k);
        else { for (int qq = 0; qq < 4; qq++) bbuf[j+qq] = (bok && k+qq < K) ? B[boff + k + qq] : 0.f; }
      }
    }
    // fragments + 48 MFMAs
    const int fr = lane & 15;
    const int kc = (lane >> 4) * 8;
    short8 ah[4], al4[4], bh[4], bl4[4];
    #pragma unroll
    for (int f = 0; f < 4; ++f){
      int ra = (wm + f * 16 + fr) * 40 + kc;
      ah[f]  = *(const short8*)&Ah[ra];
      al4[f] = *(const short8*)&Al[ra];
      int rb = (wn + f * 16 + fr) * 40 + kc;
      bh[f]  = *(const short8*)&Bh[rb];
      bl4[f] = *(const short8*)&Bl[rb];
    }
    #pragma unroll
    for (int mi = 0; mi < 4; ++mi)
      #pragma unroll
      for (int ni = 0; ni < 4; ++ni){
        acc[mi][ni] = __builtin_amdgcn_mfma_f32_16x16x32_bf16(ah[mi],  bh[ni],  acc[mi][ni], 0, 0, 0);
        acc[mi][ni] = __builtin_amdgcn_mfma_f32_16x16x32_bf16(ah[mi],  bl4[ni], acc[mi][ni], 0, 0, 0);
        acc[mi][ni] = __builtin_amdgcn_mfma_f32_16x16x32_bf16(al4[mi], bh[ni],  acc[mi][ni], 0, 0, 0);
      }
  }

  // epilogue: bias + optional gelu, guarded store
  #pragma unroll
  for (int ni = 0; ni < 4; ++ni){
    int col = tileN + wn + ni * 16 + (lane & 15);
    if (col >= N) continue;
    float bv = bias ? bias[col] : 0.f;
    #pragma unroll
    for (int mi = 0; mi < 4; ++mi){
      int row0 = tileM + wm + mi * 16 + (lane >> 4) * 4;
      #pragma unroll
      for (int r = 0; r < 4; ++r){
        int row = row0 + r;
        if (row < M){
          float v = acc[mi][ni][r] + bv;
          if (ACT == 1) v = gelu_f(v);
          C[(long)row * ldc + col] = v;
        }
      }
    }
  }
}

// ---------------- conv3 GN stats (over C3[o][b*18+l] + cb3[o]) ----------------
__global__ __launch_bounds__(256) void stats3_kernel(const float* __restrict__ C3,
                                                     const float* __restrict__ cb3,
                                                     float* __restrict__ stats){
  __shared__ float red[16];
  const int b = blockIdx.x;
  const int tid = threadIdx.x;
  float s = 0.f, q = 0.f;
  for (int idx = tid; idx < 14400; idx += 256){
    int o = idx / 18, l = idx % 18;
    float v = C3[(long)o * 1152 + b * 18 + l] + cb3[o];
    s += v; q += v * v;
  }
  block_reduce_2(s, q, red, tid);
  if (tid == 0){ stats[b * 2] = s; stats[b * 2 + 1] = q; }
}

// GN3 + GELU + transpose + positional encoding -> X[b][s][d]
__global__ __launch_bounds__(256) void trans_pe_kernel(const float* __restrict__ C3,
                                                       const float* __restrict__ cb3,
                                                       const float* __restrict__ stats,
                                                       const float* __restrict__ g3,
                                                       const float* __restrict__ b3,
                                                       const float* __restrict__ pe,
                                                       float* __restrict__ X){
  int idx = blockIdx.x * 256 + threadIdx.x;
  if (idx >= 921600) return;
  int d = idx % 800;
  int s = (idx / 800) % 18;
  int b = idx / 14400;
  float m = stats[b * 2] * (1.f / 14400.f);
  float var = stats[b * 2 + 1] * (1.f / 14400.f) - m * m;
  float rstd = rsqrtf(var + 1e-5f);
  float v = C3[(long)d * 1152 + b * 18 + s] + cb3[d];
  v = (v - m) * rstd * g3[d] + b3[d];
  X[idx] = gelu_f(v) + pe[s * 800 + d];
}

// ---------------- attention core: per (b,h) ----------------
__global__ __launch_bounds__(128) void attn_kernel(const float* __restrict__ qkv,
                                                   float* __restrict__ obuf){
  __shared__ float qL[1800], kL[1800], vL[1800], pL[324];
  const int tid = threadIdx.x;
  const int b = blockIdx.x >> 3, h = blockIdx.x & 7;
  const long basebs = ((long)b * 18) * 2400 + h * 100;
  for (int idx = tid; idx < 1800; idx += 128){
    int s = idx / 100, d = idx % 100;
    long g = basebs + (long)s * 2400 + d;
    qL[idx] = qkv[g];
    kL[idx] = qkv[g + 800];
    vL[idx] = qkv[g + 1600];
  }
  __syncthreads();
  for (int e = tid; e < 324; e += 128){
    int qi = e / 18, kj = e % 18;
    bool ok = (qi == 0) || (kj == 0) || (qi - kj <= 2 && kj - qi <= 2);
    float dot;
    if (ok){
      const float* qp = qL + qi * 100;
      const float* kp = kL + kj * 100;
      float acc = 0.f;
      for (int d = 0; d < 100; ++d) acc += qp[d] * kp[d];
      dot = acc * 0.1f;
    } else dot = -INFINITY;
    pL[e] = dot;
  }
  __syncthreads();
  if (tid < 18){
    float mx = -INFINITY;
    for (int j = 0; j < 18; j++) mx = fmaxf(mx, pL[tid * 18 + j]);
    float ex[18]; float sum = 0.f;
    for (int j = 0; j < 18; j++){ float e_ = expf(pL[tid * 18 + j] - mx); ex[j] = e_; sum += e_; }
    float inv = 1.f / sum;
    for (int j = 0; j < 18; j++) pL[tid * 18 + j] = ex[j] * inv;
  }
  __syncthreads();
  for (int idx = tid; idx < 1800; idx += 128){
    int s = idx / 100, d = idx % 100;
    const float* pp = pL + s * 18;
    float acc = 0.f;
    #pragma unroll
    for (int j = 0; j < 18; j++) acc += pp[j] * vL[j * 100 + d];
    obuf[((long)b * 18 + s) * 800 + h * 100 + d] = acc;
  }
}

// ---------------- LayerNorm: out[row] = LN(xin[row] + res[row]) * g + b ----------------
__global__ __launch_bounds__(256) void ln_kernel(const float* __restrict__ xin,
                                                 const float* __restrict__ res,
                                                 const float* __restrict__ g,
                                                 const float* __restrict__ bta,
                                                 float* __restrict__ out){
  __shared__ float red[16];
  __shared__ float mv[2];
  const int row = blockIdx.x, tid = threadIdx.x;
  const float* xp = xin + (long)row * 800;
  const float* rp = res + (long)row * 800;
  float vbuf[4];
  float s = 0.f, q = 0.f;
  #pragma unroll
  for (int u = 0; u < 4; u++){
    int d = tid + u * 256;
    float v = 0.f;
    if (d < 800){ v = xp[d] + rp[d]; s += v; q += v * v; }
    vbuf[u] = v;
  }
  block_reduce_2(s, q, red, tid);
  if (tid == 0){
    float m = s * (1.f / 800.f);
    float var = q * (1.f / 800.f) - m * m;
    mv[0] = m;
    mv[1] = rsqrtf(var + 1e-5f);
  }
  __syncthreads();
  float m = mv[0], rstd = mv[1];
  #pragma unroll
  for (int u = 0; u < 4; u++){
    int d = tid + u * 256;
    if (d < 800) out[(long)row * 800 + d] = (vbuf[u] - m) * rstd * g[d] + bta[d];
  }
}

// ---------------- host launch ----------------
extern "C" void kernel_launch(void* const* d_in, const int* in_sizes, int n_in,
                              void* d_out, int out_size, void* d_ws, size_t ws_size,
                              hipStream_t stream){
  const float* src    = (const float*)d_in[0];
  const float* cw1    = (const float*)d_in[1];
  const float* cb1    = (const float*)d_in[2];
  const float* gn1_g  = (const float*)d_in[3];
  const float* gn1_b  = (const float*)d_in[4];
  const float* cw2    = (const float*)d_in[5];
  const float* cb2    = (const float*)d_in[6];
  const float* gn2_g  = (const float*)d_in[7];
  const float* gn2_b  = (const float*)d_in[8];
  const float* cw3    = (const float*)d_in[9];
  const float* cb3    = (const float*)d_in[10];
  const float* gn3_g  = (const float*)d_in[11];
  const float* gn3_b  = (const float*)d_in[12];
  const float* ipw    = (const float*)d_in[13];
  const float* ipb    = (const float*)d_in[14];
  const float* aow    = (const float*)d_in[15];
  const float* aob    = (const float*)d_in[16];
  const float* l1w    = (const float*)d_in[17];
  const float* l1b    = (const float*)d_in[18];
  const float* l2w    = (const float*)d_in[19];
  const float* l2b    = (const float*)d_in[20];
  const float* ln1g   = (const float*)d_in[21];
  const float* ln1b   = (const float*)d_in[22];
  const float* ln2g   = (const float*)d_in[23];
  const float* ln2b   = (const float*)d_in[24];
  const float* outw   = (const float*)d_in[25];
  const float* outb   = (const float*)d_in[26];

  float* ws = (float*)d_ws;
  float* pe    = ws + OFF_PE;
  float* stats = ws + OFF_STATS;
  float* wr1   = ws + OFF_WR1;
  float* c1    = ws + OFF_C1;
  float* c2    = ws + OFF_C2;
  float* P     = ws + OFF_P;
  float* C3    = ws + OFF_C3;
  float* X     = ws + OFF_X;
  float* XA    = ws + OFF_XA;
  float* QKV   = ws + OFF_QKV;
  float* O     = ws + OFF_O;
  float* AB    = ws + OFF_AB;
  float* HB    = ws + OFF_H;

  zero_kernel<<<2, 256, 0, stream>>>(stats, 512);
  relayout_w1_kernel<<<76, 256, 0, stream>>>(cw1, wr1);
  pe_kernel<<<57, 256, 0, stream>>>(pe);

  // conv stack
  conv1_kernel<<<dim3(8, 64), 256, 0, stream>>>(src, wr1, cb1, c1, stats);
  gn_gelu_kernel<<<3600, 256, 0, stream>>>(c1, stats, gn1_g, gn1_b, 1800, 14400);
  conv2_kernel<<<dim3(57, 64), 256, 0, stream>>>(c1, cw2, cb2, c2, stats + 128);
  gn_gelu_kernel<<<3600, 256, 0, stream>>>(c2, stats + 128, gn2_g, gn2_b, 180, 14400);
  im2col_kernel<<<18360, 256, 0, stream>>>(c2, P);
  // conv3 as GEMM: [800 x 4080] @ [4080 x 1152]
  gemm_split<0><<<dim3(9, 7), 256, 0, stream>>>(cw3, P, nullptr, C3, 800, 1152, 4080, 4080, 4096, 1152);
  stats3_kernel<<<64, 256, 0, stream>>>(C3, cb3, stats + 256);
  trans_pe_kernel<<<3600, 256, 0, stream>>>(C3, cb3, stats + 256, gn3_g, gn3_b, pe, X);

  // transformer layers
  for (int i = 0; i < NLAYER; ++i){
    gemm_split<0><<<dim3(19, 9), 256, 0, stream>>>(X, ipw + (long)i * 2400 * 800, ipb + (long)i * 2400,
                                                   QKV, 1152, 2400, 800, 800, 800, 2400);
    attn_kernel<<<512, 128, 0, stream>>>(QKV, O);
    gemm_split<0><<<dim3(7, 9), 256, 0, stream>>>(O, aow + (long)i * 800 * 800, aob + (long)i * 800,
                                                  AB, 1152, 800, 800, 800, 800, 800);
    ln_kernel<<<1152, 256, 0, stream>>>(X, AB, ln1g + (long)i * 800, ln1b + (long)i * 800, XA);
    gemm_split<1><<<dim3(25, 9), 256, 0, stream>>>(XA, l1w + (long)i * 3200 * 800, l1b + (long)i * 3200,
                                                   HB, 1152, 3200, 800, 800, 800, 3200);
    gemm_split<0><<<dim3(7, 9), 256, 0, stream>>>(HB, l2w + (long)i * 800 * 3200, l2b + (long)i * 800,
                                                  AB, 1152, 800, 3200, 3200, 3200, 800);
    ln_kernel<<<1152, 256, 0, stream>>>(XA, AB, ln2g + (long)i * 800, ln2b + (long)i * 800, X);
  }

  // final projection -> d_out
  gemm_split<0><<<dim3(7, 9), 256, 0, stream>>>(X, outw, outb, (float*)d_out,
                                                1152, 800, 800, 800, 800, 800);
}

// Round 3
// 2396.911 us; speedup vs baseline: 1.8944x; 1.8944x over previous
//
#include <hip/hip_runtime.h>
#include <hip/hip_bf16.h>
#include <math.h>

#define BATCH 64
#define SEQ   18
#define DMODEL 800
#define NLAYER 8

typedef short short8 __attribute__((ext_vector_type(8)));
typedef float f32x4 __attribute__((ext_vector_type(4)));

// ---------------- workspace layout (floats) ----------------
#define OFF_PE    0L
#define OFF_STATS 14400L
#define OFF_WR1   14912L        // 19328
#define OFF_W2P   34240L        // 128*832 = 106496
#define OFF_C1    140736L       // 921600
#define OFF_C2    1062336L      // c2g [80][11520]
#define OFF_C3    1983936L      // [800][1152]
#define OFF_X     2905536L
#define OFF_XA    3827136L
#define OFF_O     4748736L
#define OFF_AB    5670336L
#define OFF_U     6591936L      // union region, 9584640 floats
// P2   = U + 0        (11520*832 = 9584640)   [conv2 phase]
// P3   = U + 0        (1152*4096 = 4718592)   [conv3 phase]
// CW3P = U + 4718592  (896*4096  = 3670016)   [conv3 phase]
// QKV  = U + 0        (2764800)               [transformer]
// HB   = U + 2764800  (3686400)               [transformer]
// end = 16,176,576 floats = 64.7 MB

// ---------------- helpers ----------------
__device__ __forceinline__ float gelu_f(float x){
  float u = 0.7978845608028654f * (x + 0.044715f * x * x * x);
  return 0.5f * x * (1.0f + tanhf(u));
}

__device__ __forceinline__ void split8(const float* v, short8 &h8, short8 &l8){
  #pragma unroll
  for (int j = 0; j < 8; j++){
    unsigned int u = __float_as_uint(v[j]);
    unsigned int hr = (u + 0x8000u) & 0xFFFF0000u;  // half-up rounded hi
    float hf = __uint_as_float(hr);
    float lf = v[j] - hf;
    h8[j] = (short)(hr >> 16);
    l8[j] = (short)(__float_as_uint(lf) >> 16);     // trunc lo
  }
}

__device__ __forceinline__ void block_reduce_2(float &s, float &q, float* red, int tid){
  #pragma unroll
  for (int off = 32; off > 0; off >>= 1){
    s += __shfl_down(s, off, 64);
    q += __shfl_down(q, off, 64);
  }
  int w = tid >> 6;
  if ((tid & 63) == 0){ red[w] = s; red[8 + w] = q; }
  __syncthreads();
  if (tid == 0){
    float ss = 0.f, qq = 0.f;
    int nw = blockDim.x >> 6;
    for (int i = 0; i < nw; ++i){ ss += red[i]; qq += red[8 + i]; }
    s = ss; q = qq;
  }
}

// ---------------- utility kernels ----------------
__global__ __launch_bounds__(256) void zero_kernel(float* p, int n){
  int i = blockIdx.x * 256 + threadIdx.x;
  if (i < n) p[i] = 0.f;
}

__global__ __launch_bounds__(256) void relayout_w1_kernel(const float* __restrict__ w1, float* __restrict__ wr){
  int idx = blockIdx.x * 256 + threadIdx.x;
  if (idx >= 8 * 12 * 201) return;
  int o = idx / 2412, rem = idx % 2412, i = rem / 201, t = rem % 201;
  wr[(i * 201 + t) * 8 + o] = w1[idx];
}

__global__ __launch_bounds__(256) void pe_kernel(float* __restrict__ pe){
  int idx = blockIdx.x * 256 + threadIdx.x;
  if (idx >= SEQ * DMODEL) return;
  int s = idx / DMODEL, d = idx % DMODEL;
  int j = d >> 1;
  float div = expf(-9.210340371976184f * (float)(2 * j) / 800.f);
  float a = (float)s * div;
  pe[idx] = (d & 1) ? cosf(a) : sinf(a);
}

__global__ __launch_bounds__(256) void w2pad_kernel(const float* __restrict__ w2, float* __restrict__ wp){
  int idx = blockIdx.x * 256 + threadIdx.x;
  if (idx >= 128 * 832) return;
  int o = idx / 832, k = idx % 832;
  wp[idx] = (o < 80 && k < 808) ? w2[o * 808 + k] : 0.f;
}

__global__ __launch_bounds__(256) void cw3pad_kernel(const float* __restrict__ w3, float* __restrict__ wp){
  int idx = blockIdx.x * 256 + threadIdx.x;
  if (idx >= 896 * 4096) return;
  int o = idx / 4096, k = idx % 4096;
  wp[idx] = (o < 800 && k < 4080) ? w3[(long)o * 4080 + k] : 0.f;
}

// ---------------- conv1 ----------------
__global__ __launch_bounds__(256) void conv1_kernel(const float* __restrict__ src,
                                                    const float* __restrict__ wr,
                                                    const float* __restrict__ cb1,
                                                    float* __restrict__ out,
                                                    float* __restrict__ stats){
  __shared__ float sL[12 * 1480];
  __shared__ float red[16];
  const int tid = threadIdx.x;
  const int b = blockIdx.y;
  const int l0 = blockIdx.x * 256;
  const int sstart = 5 * l0 - 100;
  for (int idx = tid; idx < 12 * 1480; idx += 256){
    int i = idx / 1480, u = idx % 1480;
    int p = sstart + u;
    sL[idx] = (p >= 0 && p < 9000) ? src[((long)b * 12 + i) * 9000 + p] : 0.f;
  }
  __syncthreads();
  const int l = l0 + tid;
  float acc[8];
  #pragma unroll
  for (int o = 0; o < 8; o++) acc[o] = cb1[o];
  {
    const int base = 5 * tid;
    for (int i = 0; i < 12; i++){
      const float* sp = sL + i * 1480 + base;
      const float* wp = wr + i * 201 * 8;
      for (int t = 0; t < 201; t++){
        float x = sp[t];
        const float4 w0 = *(const float4*)(wp + t * 8);
        const float4 w1 = *(const float4*)(wp + t * 8 + 4);
        acc[0] += x * w0.x; acc[1] += x * w0.y; acc[2] += x * w0.z; acc[3] += x * w0.w;
        acc[4] += x * w1.x; acc[5] += x * w1.y; acc[6] += x * w1.z; acc[7] += x * w1.w;
      }
    }
  }
  float s = 0.f, q = 0.f;
  if (l < 1800){
    #pragma unroll
    for (int o = 0; o < 8; o++){
      out[((long)b * 8 + o) * 1800 + l] = acc[o];
      s += acc[o]; q += acc[o] * acc[o];
    }
  }
  block_reduce_2(s, q, red, tid);
  if (tid == 0){
    atomicAdd(&stats[b * 2 + 0], s);
    atomicAdd(&stats[b * 2 + 1], q);
  }
}

// GroupNorm finalize + GELU for c1 layout [b][c][L]
__global__ __launch_bounds__(256) void gn_gelu_kernel(float* __restrict__ x,
                                                      const float* __restrict__ stats,
                                                      const float* __restrict__ g,
                                                      const float* __restrict__ bta,
                                                      int L, int n_per_b){
  long idx = (long)blockIdx.x * 256 + threadIdx.x;
  long total = (long)BATCH * n_per_b;
  if (idx >= total) return;
  int b = (int)(idx / n_per_b);
  int rem = (int)(idx % n_per_b);
  int c = rem / L;
  float inv_n = 1.f / (float)n_per_b;
  float m = stats[b * 2] * inv_n;
  float var = stats[b * 2 + 1] * inv_n - m * m;
  float rstd = rsqrtf(var + 1e-5f);
  float v = x[idx];
  v = (v - m) * rstd * g[c] + bta[c];
  x[idx] = gelu_f(v);
}

// ---------------- im2col for conv2: P2[n=b*180+l][k=i*101+t], ld 832 ----------------
__global__ __launch_bounds__(256) void im2col2_kernel(const float* __restrict__ c1, float* __restrict__ P){
  int idx = blockIdx.x * 256 + threadIdx.x;
  if (idx >= 11520 * 832) return;
  int n = idx / 832, k = idx % 832;
  float v = 0.f;
  if (k < 808){
    int b = n / 180, l = n % 180;
    int i = k / 101, t = k % 101;
    int p = 10 * l - 50 + t;
    if (p >= 0 && p < 1800) v = c1[((long)b * 8 + i) * 1800 + p];
  }
  P[(long)n * 832 + k] = v;
}

// conv2 GN stats over raw C2g[o][b*180+l] + cb2[o]
__global__ __launch_bounds__(256) void stats2_kernel(const float* __restrict__ C2,
                                                     const float* __restrict__ cb2,
                                                     float* __restrict__ stats){
  __shared__ float red[16];
  const int b = blockIdx.x;
  const int tid = threadIdx.x;
  float s = 0.f, q = 0.f;
  for (int idx = tid; idx < 14400; idx += 256){
    int o = idx / 180, l = idx % 180;
    float v = C2[(long)o * 11520 + b * 180 + l] + cb2[o];
    s += v; q += v * v;
  }
  block_reduce_2(s, q, red, tid);
  if (tid == 0){ stats[b * 2] = s; stats[b * 2 + 1] = q; }
}

// ---------------- im2col for conv3 with fused GN2+GELU ----------------
// P3[n=b*18+l][k=i*51+t], ld 4096; reads raw c2g, applies (x+cb2-m)*rstd*g+b then gelu.
__global__ __launch_bounds__(256) void im2col3_kernel(const float* __restrict__ c2,
                                                      const float* __restrict__ cb2,
                                                      const float* __restrict__ stats,
                                                      const float* __restrict__ g2,
                                                      const float* __restrict__ b2,
                                                      float* __restrict__ P){
  int idx = blockIdx.x * 256 + threadIdx.x;
  if (idx >= 1152 * 4096) return;
  int n = idx >> 12, k = idx & 4095;
  float v = 0.f;
  if (k < 4080){
    int b = n / 18, l = n % 18;
    int i = k / 51, t = k % 51;
    int p = 10 * l - 25 + t;
    if (p >= 0 && p < 180){
      float m = stats[b * 2] * (1.f / 14400.f);
      float var = stats[b * 2 + 1] * (1.f / 14400.f) - m * m;
      float rstd = rsqrtf(var + 1e-5f);
      float raw = c2[(long)i * 11520 + b * 180 + p] + cb2[i];
      v = gelu_f((raw - m) * rstd * g2[i] + b2[i]);
    }
  }
  P[(long)n * 4096 + k] = v;
}

// ---------------- split-bf16 MFMA GEMM v2: 64x64 tile, BK=32, 4 waves ----------------
// C[m][n] = sum_k A[m][k]*B[n][k] (+bias[n]); A rows must be readable for full tiles.
#define LOADT(da, db, kk) do { \
    *(float4*)&da[0] = *(const float4*)(Ap + (kk)); \
    *(float4*)&da[4] = *(const float4*)(Ap + (kk) + 4); \
    if (bok){ \
      *(float4*)&db[0] = *(const float4*)(Bp + (kk)); \
      *(float4*)&db[4] = *(const float4*)(Bp + (kk) + 4); \
    } else { \
      _Pragma("unroll") for (int j_ = 0; j_ < 8; j_++) db[j_] = 0.f; \
    } \
  } while(0)

#define CONV_STORE(ba, bb) do { \
    short8 h_, l_; \
    split8(ba, h_, l_); \
    *(short8*)&Ah[sbase] = h_; *(short8*)&Al[sbase] = l_; \
    split8(bb, h_, l_); \
    *(short8*)&Bh[sbase] = h_; *(short8*)&Bl[sbase] = l_; \
  } while(0)

#define FRAG_MFMA() do { \
    short8 ah_[2], al_[2], bh_[2], bl_[2]; \
    _Pragma("unroll") for (int f = 0; f < 2; ++f){ \
      int ra = (wm + f * 16 + fr) * 40 + kc; \
      ah_[f] = *(const short8*)&Ah[ra]; \
      al_[f] = *(const short8*)&Al[ra]; \
      int rb = (wn + f * 16 + fr) * 40 + kc; \
      bh_[f] = *(const short8*)&Bh[rb]; \
      bl_[f] = *(const short8*)&Bl[rb]; \
    } \
    _Pragma("unroll") for (int mi = 0; mi < 2; ++mi) \
      _Pragma("unroll") for (int ni = 0; ni < 2; ++ni){ \
        acc[mi][ni] = __builtin_amdgcn_mfma_f32_16x16x32_bf16(ah_[mi], bh_[ni], acc[mi][ni], 0, 0, 0); \
        acc[mi][ni] = __builtin_amdgcn_mfma_f32_16x16x32_bf16(ah_[mi], bl_[ni], acc[mi][ni], 0, 0, 0); \
        acc[mi][ni] = __builtin_amdgcn_mfma_f32_16x16x32_bf16(al_[mi], bh_[ni], acc[mi][ni], 0, 0, 0); \
      } \
  } while(0)

template<int ACT, int K>
__global__ __launch_bounds__(256, 2)
void gemm_split(const float* __restrict__ A, const float* __restrict__ B,
                const float* __restrict__ bias, float* __restrict__ C,
                int M, int N, int lda, int ldb, int ldc){
  constexpr int NT = K / 32;
  __shared__ unsigned short Ah[64 * 40], Al[64 * 40], Bh[64 * 40], Bl[64 * 40];
  const int tid = threadIdx.x;
  const int lane = tid & 63;
  const int wid = tid >> 6;
  const int wm = (wid & 1) * 32, wn = (wid >> 1) * 32;
  const int tileM = blockIdx.y * 64, tileN = blockIdx.x * 64;
  const int sr = tid >> 2;          // staging row 0..63
  const int q  = tid & 3;           // k-quarter
  const int sbase = sr * 40 + q * 8;
  const int fr = lane & 15;
  const int kc = (lane >> 4) * 8;
  const float* Ap = A + (long)(tileM + sr) * lda + q * 8;
  const float* Bp = B + (long)(tileN + sr) * ldb + q * 8;
  const bool bok = (tileN + sr) < N;

  float a0[8], b0[8], a1[8], b1[8];
  f32x4 acc[2][2];
  #pragma unroll
  for (int i = 0; i < 2; i++)
    #pragma unroll
    for (int j = 0; j < 2; j++)
      acc[i][j] = (f32x4){0.f, 0.f, 0.f, 0.f};

  LOADT(a0, b0, 0);
  for (int kt = 0; kt < NT; kt += 2){
    if (kt + 1 < NT) LOADT(a1, b1, (kt + 1) * 32);
    __syncthreads();
    CONV_STORE(a0, b0);
    __syncthreads();
    FRAG_MFMA();
    if (kt + 1 < NT){
      if (kt + 2 < NT) LOADT(a0, b0, (kt + 2) * 32);
      __syncthreads();
      CONV_STORE(a1, b1);
      __syncthreads();
      FRAG_MFMA();
    }
  }

  #pragma unroll
  for (int ni = 0; ni < 2; ++ni){
    int col = tileN + wn + ni * 16 + (lane & 15);
    if (col < N){
      float bv = bias ? bias[col] : 0.f;
      #pragma unroll
      for (int mi = 0; mi < 2; ++mi){
        int row0 = tileM + wm + mi * 16 + (lane >> 4) * 4;
        #pragma unroll
        for (int r = 0; r < 4; ++r){
          int row = row0 + r;
          if (row < M){
            float v = acc[mi][ni][r] + bv;
            if (ACT == 1) v = gelu_f(v);
            C[(long)row * ldc + col] = v;
          }
        }
      }
    }
  }
}

// ---------------- conv3 GN stats + fused transpose/PE ----------------
__global__ __launch_bounds__(256) void stats3_kernel(const float* __restrict__ C3,
                                                     const float* __restrict__ cb3,
                                                     float* __restrict__ stats){
  __shared__ float red[16];
  const int b = blockIdx.x;
  const int tid = threadIdx.x;
  float s = 0.f, q = 0.f;
  for (int idx = tid; idx < 14400; idx += 256){
    int o = idx / 18, l = idx % 18;
    float v = C3[(long)o * 1152 + b * 18 + l] + cb3[o];
    s += v; q += v * v;
  }
  block_reduce_2(s, q, red, tid);
  if (tid == 0){ stats[b * 2] = s; stats[b * 2 + 1] = q; }
}

__global__ __launch_bounds__(256) void trans_pe_kernel(const float* __restrict__ C3,
                                                       const float* __restrict__ cb3,
                                                       const float* __restrict__ stats,
                                                       const float* __restrict__ g3,
                                                       const float* __restrict__ b3,
                                                       const float* __restrict__ pe,
                                                       float* __restrict__ X){
  int idx = blockIdx.x * 256 + threadIdx.x;
  if (idx >= 921600) return;
  int d = idx % 800;
  int s = (idx / 800) % 18;
  int b = idx / 14400;
  float m = stats[b * 2] * (1.f / 14400.f);
  float var = stats[b * 2 + 1] * (1.f / 14400.f) - m * m;
  float rstd = rsqrtf(var + 1e-5f);
  float v = C3[(long)d * 1152 + b * 18 + s] + cb3[d];
  v = (v - m) * rstd * g3[d] + b3[d];
  X[idx] = gelu_f(v) + pe[s * 800 + d];
}

// ---------------- attention core ----------------
__global__ __launch_bounds__(128) void attn_kernel(const float* __restrict__ qkv,
                                                   float* __restrict__ obuf){
  __shared__ float qL[1800], kL[1800], vL[1800], pL[324];
  const int tid = threadIdx.x;
  const int b = blockIdx.x >> 3, h = blockIdx.x & 7;
  const long basebs = ((long)b * 18) * 2400 + h * 100;
  for (int idx = tid; idx < 1800; idx += 128){
    int s = idx / 100, d = idx % 100;
    long g = basebs + (long)s * 2400 + d;
    qL[idx] = qkv[g];
    kL[idx] = qkv[g + 800];
    vL[idx] = qkv[g + 1600];
  }
  __syncthreads();
  for (int e = tid; e < 324; e += 128){
    int qi = e / 18, kj = e % 18;
    bool ok = (qi == 0) || (kj == 0) || (qi - kj <= 2 && kj - qi <= 2);
    float dot;
    if (ok){
      const float* qp = qL + qi * 100;
      const float* kp = kL + kj * 100;
      float acc = 0.f;
      for (int d = 0; d < 100; ++d) acc += qp[d] * kp[d];
      dot = acc * 0.1f;
    } else dot = -INFINITY;
    pL[e] = dot;
  }
  __syncthreads();
  if (tid < 18){
    float mx = -INFINITY;
    for (int j = 0; j < 18; j++) mx = fmaxf(mx, pL[tid * 18 + j]);
    float ex[18]; float sum = 0.f;
    for (int j = 0; j < 18; j++){ float e_ = expf(pL[tid * 18 + j] - mx); ex[j] = e_; sum += e_; }
    float inv = 1.f / sum;
    for (int j = 0; j < 18; j++) pL[tid * 18 + j] = ex[j] * inv;
  }
  __syncthreads();
  for (int idx = tid; idx < 1800; idx += 128){
    int s = idx / 100, d = idx % 100;
    const float* pp = pL + s * 18;
    float acc = 0.f;
    #pragma unroll
    for (int j = 0; j < 18; j++) acc += pp[j] * vL[j * 100 + d];
    obuf[((long)b * 18 + s) * 800 + h * 100 + d] = acc;
  }
}

// ---------------- LayerNorm ----------------
__global__ __launch_bounds__(256) void ln_kernel(const float* __restrict__ xin,
                                                 const float* __restrict__ res,
                                                 const float* __restrict__ g,
                                                 const float* __restrict__ bta,
                                                 float* __restrict__ out){
  __shared__ float red[16];
  __shared__ float mv[2];
  const int row = blockIdx.x, tid = threadIdx.x;
  const float* xp = xin + (long)row * 800;
  const float* rp = res + (long)row * 800;
  float vbuf[4];
  float s = 0.f, q = 0.f;
  #pragma unroll
  for (int u = 0; u < 4; u++){
    int d = tid + u * 256;
    float v = 0.f;
    if (d < 800){ v = xp[d] + rp[d]; s += v; q += v * v; }
    vbuf[u] = v;
  }
  block_reduce_2(s, q, red, tid);
  if (tid == 0){
    float m = s * (1.f / 800.f);
    float var = q * (1.f / 800.f) - m * m;
    mv[0] = m;
    mv[1] = rsqrtf(var + 1e-5f);
  }
  __syncthreads();
  float m = mv[0], rstd = mv[1];
  #pragma unroll
  for (int u = 0; u < 4; u++){
    int d = tid + u * 256;
    if (d < 800) out[(long)row * 800 + d] = (vbuf[u] - m) * rstd * g[d] + bta[d];
  }
}

// ---------------- host launch ----------------
extern "C" void kernel_launch(void* const* d_in, const int* in_sizes, int n_in,
                              void* d_out, int out_size, void* d_ws, size_t ws_size,
                              hipStream_t stream){
  const float* src    = (const float*)d_in[0];
  const float* cw1    = (const float*)d_in[1];
  const float* cb1    = (const float*)d_in[2];
  const float* gn1_g  = (const float*)d_in[3];
  const float* gn1_b  = (const float*)d_in[4];
  const float* cw2    = (const float*)d_in[5];
  const float* cb2    = (const float*)d_in[6];
  const float* gn2_g  = (const float*)d_in[7];
  const float* gn2_b  = (const float*)d_in[8];
  const float* cw3    = (const float*)d_in[9];
  const float* cb3    = (const float*)d_in[10];
  const float* gn3_g  = (const float*)d_in[11];
  const float* gn3_b  = (const float*)d_in[12];
  const float* ipw    = (const float*)d_in[13];
  const float* ipb    = (const float*)d_in[14];
  const float* aow    = (const float*)d_in[15];
  const float* aob    = (const float*)d_in[16];
  const float* l1w    = (const float*)d_in[17];
  const float* l1b    = (const float*)d_in[18];
  const float* l2w    = (const float*)d_in[19];
  const float* l2b    = (const float*)d_in[20];
  const float* ln1g   = (const float*)d_in[21];
  const float* ln1b   = (const float*)d_in[22];
  const float* ln2g   = (const float*)d_in[23];
  const float* ln2b   = (const float*)d_in[24];
  const float* outw   = (const float*)d_in[25];
  const float* outb   = (const float*)d_in[26];

  float* ws = (float*)d_ws;
  float* pe    = ws + OFF_PE;
  float* stats = ws + OFF_STATS;
  float* wr1   = ws + OFF_WR1;
  float* w2p   = ws + OFF_W2P;
  float* c1    = ws + OFF_C1;
  float* c2g   = ws + OFF_C2;
  float* C3    = ws + OFF_C3;
  float* X     = ws + OFF_X;
  float* XA    = ws + OFF_XA;
  float* O     = ws + OFF_O;
  float* AB    = ws + OFF_AB;
  float* U     = ws + OFF_U;
  float* P2    = U;
  float* P3    = U;
  float* cw3p  = U + 4718592L;
  float* QKV   = U;
  float* HB    = U + 2764800L;

  zero_kernel<<<2, 256, 0, stream>>>(stats, 512);
  relayout_w1_kernel<<<76, 256, 0, stream>>>(cw1, wr1);
  pe_kernel<<<57, 256, 0, stream>>>(pe);
  w2pad_kernel<<<416, 256, 0, stream>>>(cw2, w2p);

  // conv1
  conv1_kernel<<<dim3(8, 64), 256, 0, stream>>>(src, wr1, cb1, c1, stats);
  gn_gelu_kernel<<<3600, 256, 0, stream>>>(c1, stats, gn1_g, gn1_b, 1800, 14400);

  // conv2 as GEMM
  im2col2_kernel<<<37440, 256, 0, stream>>>(c1, P2);
  gemm_split<0, 832><<<dim3(180, 2), 256, 0, stream>>>(w2p, P2, nullptr, c2g, 80, 11520, 832, 832, 11520);
  stats2_kernel<<<64, 256, 0, stream>>>(c2g, cb2, stats + 128);

  // conv3 as GEMM (GN2+GELU fused into im2col3)
  cw3pad_kernel<<<14336, 256, 0, stream>>>(cw3, cw3p);
  im2col3_kernel<<<18432, 256, 0, stream>>>(c2g, cb2, stats + 128, gn2_g, gn2_b, P3);
  gemm_split<0, 4096><<<dim3(18, 13), 256, 0, stream>>>(cw3p, P3, nullptr, C3, 800, 1152, 4096, 4096, 1152);
  stats3_kernel<<<64, 256, 0, stream>>>(C3, cb3, stats + 256);
  trans_pe_kernel<<<3600, 256, 0, stream>>>(C3, cb3, stats + 256, gn3_g, gn3_b, pe, X);

  // transformer layers
  for (int i = 0; i < NLAYER; ++i){
    gemm_split<0, 800><<<dim3(38, 18), 256, 0, stream>>>(X, ipw + (long)i * 2400 * 800, ipb + (long)i * 2400,
                                                         QKV, 1152, 2400, 800, 800, 2400);
    attn_kernel<<<512, 128, 0, stream>>>(QKV, O);
    gemm_split<0, 800><<<dim3(13, 18), 256, 0, stream>>>(O, aow + (long)i * 800 * 800, aob + (long)i * 800,
                                                         AB, 1152, 800, 800, 800, 800);
    ln_kernel<<<1152, 256, 0, stream>>>(X, AB, ln1g + (long)i * 800, ln1b + (long)i * 800, XA);
    gemm_split<1, 800><<<dim3(50, 18), 256, 0, stream>>>(XA, l1w + (long)i * 3200 * 800, l1b + (long)i * 3200,
                                                         HB, 1152, 3200, 800, 800, 3200);
    gemm_split<0, 3200><<<dim3(13, 18), 256, 0, stream>>>(HB, l2w + (long)i * 800 * 3200, l2b + (long)i * 800,
                                                          AB, 1152, 800, 3200, 3200, 800);
    ln_kernel<<<1152, 256, 0, stream>>>(XA, AB, ln2g + (long)i * 800, ln2b + (long)i * 800, X);
  }

  gemm_split<0, 800><<<dim3(13, 18), 256, 0, stream>>>(X, outw, outb, (float*)d_out,
                                                       1152, 800, 800, 800, 800);
}